// Round 2
// baseline (15998.225 us; speedup 1.0000x reference)
//
#include <hip/hip_runtime.h>
#include <hip/hip_bf16.h>

// All tensors are float32 on device (per reference dtypes). f32 math throughout.

#define B_   64
#define S_   12
#define N_   170
#define BN_  (B_*N_)      // 10880
#define E_   128
#define L_   4
#define C_   2
#define H_   8
#define DH_  16
#define FF_  512
#define EPS_ 1e-5f

// ---------------- embed + positional encoding ----------------
// h[bn][s][e] = x[b,s,n,0]*emb_w[e] + emb_b[e] + pe[s][e],  bn = b*N_+n
__global__ void k_embed(const float* __restrict__ x, const float* __restrict__ emb_w,
                        const float* __restrict__ emb_b, const float* __restrict__ pe,
                        float* __restrict__ h) {
    int idx = blockIdx.x * 256 + threadIdx.x;     // exact: BN_*S_*E_ threads
    int e  = idx & (E_-1);
    int se = idx >> 7;
    int s  = se % S_;
    int bn = se / S_;
    int b = bn / N_, n = bn % N_;
    float xv = x[(b*S_ + s)*N_ + n];
    h[idx] = xv * emb_w[e] + emb_b[e] + pe[s*E_ + e];
}

// ---------------- conv-weight transpose (to [k][e][o]) ----------------
// conv_q_w (L,E,E,3) -> cqT[l][k<2][e][o]   (k=2 tap masked out: OFFSET=0)
// conv_k_w (L,C,E,E,3) -> ckT[l][i][k<3][e][o]
__global__ void k_wtrans(const float* __restrict__ cq, const float* __restrict__ ck,
                         float* __restrict__ cqT, float* __restrict__ ckT) {
    int idx = blockIdx.x * 256 + threadIdx.x;
    const int NQ = L_*2*E_*E_;     // 131072
    const int NK = L_*C_*3*E_*E_;  // 393216
    if (idx < NQ) {
        int o = idx & (E_-1), e = (idx>>7) & (E_-1), k = (idx>>14) & 1, l = idx >> 15;
        cqT[idx] = cq[((l*E_ + o)*E_ + e)*3 + k];
    } else if (idx < NQ + NK) {
        int i2 = idx - NQ;
        int o = i2 & (E_-1), e = (i2>>7) & (E_-1);
        int lik = i2 >> 14;              // li*3 + k,  li = l*C_+i
        int k = lik % 3, li = lik / 3;
        ckT[i2] = ck[((li*E_ + o)*E_ + e)*3 + k];
    }
}

// ---------------- layernorm helper (per-wave, 3 rows each) ----------------
__device__ __forceinline__ void ln_write(const float (*t2)[E_], const float* __restrict__ g,
                                         const float* __restrict__ bb, float* outp, int t) {
    int wid = t >> 6, lane = t & 63;
    #pragma unroll
    for (int r0 = 0; r0 < 3; r0++) {
        int r = wid*3 + r0;
        float x0 = t2[r][lane], x1 = t2[r][lane+64];
        float s = x0 + x1;
        #pragma unroll
        for (int off = 32; off; off >>= 1) s += __shfl_xor(s, off);
        float m = s * (1.f/E_);
        float d0 = x0 - m, d1 = x1 - m;
        float s2 = d0*d0 + d1*d1;
        #pragma unroll
        for (int off = 32; off; off >>= 1) s2 += __shfl_xor(s2, off);
        float inv = rsqrtf(s2 * (1.f/E_) + EPS_);
        outp[r*E_ + lane]    = d0*inv*g[lane]    + bb[lane];
        outp[r*E_ + lane+64] = d1*inv*g[lane+64] + bb[lane+64];
    }
}

// ---------------- fused: masked conv + self-attention + residual + LN ----------------
// cqw: [2][E][E] ([k][e][o]) for this layer; w: sa_w[l] = [4][E][E]; b: sa_b[l] = [4][E]
__global__ void __launch_bounds__(256)
k_selfattn(float* h, const float* __restrict__ cqw,
           const float* __restrict__ w, const float* __restrict__ b,
           const float* __restrict__ lg, const float* __restrict__ lb) {
    __shared__ float hraw[S_][E_];
    __shared__ float hs[S_][E_];              // conv output (residual base)
    __shared__ float qkv[3][S_][E_+1];
    __shared__ float ao[S_][E_+1];
    __shared__ float t2[S_][E_];
    int bn = blockIdx.x, t = threadIdx.x;
    float* hp = h + (size_t)bn * (S_*E_);
    for (int i = t; i < S_*E_; i += 256) hraw[i>>7][i&(E_-1)] = hp[i];
    __syncthreads();
    const int o = t & (E_-1), sg = t >> 7;
    {   // causal masked conv, taps k=0 (x[s-1]) and k=1 (x[s])
        float acc[6];
        #pragma unroll
        for (int r = 0; r < 6; r++) acc[r] = 0.f;
        for (int e = 0; e < E_; e++) {
            float w0 = cqw[e*E_ + o];
            float w1 = cqw[(E_ + e)*E_ + o];
            #pragma unroll
            for (int r = 0; r < 6; r++) {
                int s = sg*6 + r;
                if (s >= 1) acc[r] += w0 * hraw[s-1][e];
                acc[r] += w1 * hraw[s][e];
            }
        }
        #pragma unroll
        for (int r = 0; r < 6; r++) hs[sg*6+r][o] = acc[r];
    }
    __syncthreads();
    for (int j = 0; j < 3; j++) {
        const float* wj = w + j*E_*E_;
        float bj = b[j*E_ + o];
        float acc[6];
        #pragma unroll
        for (int r = 0; r < 6; r++) acc[r] = bj;
        for (int e = 0; e < E_; e++) {
            float wv = wj[e*E_ + o];
            #pragma unroll
            for (int r = 0; r < 6; r++) acc[r] += wv * hs[sg*6+r][e];
        }
        #pragma unroll
        for (int r = 0; r < 6; r++) qkv[j][sg*6+r][o] = acc[r];
    }
    __syncthreads();
    if (t < H_*S_) {                          // 96 threads: (head, q-row)
        int qi = t % S_, hh = t / S_, hb = hh*DH_;
        float sc[S_], mx = -1e30f;
        #pragma unroll
        for (int j = 0; j < S_; j++) {
            float s = 0.f;
            #pragma unroll
            for (int d = 0; d < DH_; d++) s += qkv[0][qi][hb+d] * qkv[1][j][hb+d];
            s *= 0.25f;                        // 1/sqrt(16)
            if (j > qi) s = -1e30f;            // causal mask
            sc[j] = s; mx = fmaxf(mx, s);
        }
        float sum = 0.f;
        #pragma unroll
        for (int j = 0; j < S_; j++) { sc[j] = expf(sc[j]-mx); sum += sc[j]; }
        float inv = 1.f / sum;
        #pragma unroll
        for (int d = 0; d < DH_; d++) {
            float ov = 0.f;
            #pragma unroll
            for (int j = 0; j < S_; j++) ov += sc[j] * qkv[2][j][hb+d];
            ao[qi][hb+d] = ov * inv;
        }
    }
    __syncthreads();
    {
        const float* w3 = w + 3*E_*E_;
        float b3 = b[3*E_ + o];
        float acc[6];
        #pragma unroll
        for (int r = 0; r < 6; r++) acc[r] = b3;
        for (int e = 0; e < E_; e++) {
            float wv = w3[e*E_ + o];
            #pragma unroll
            for (int r = 0; r < 6; r++) acc[r] += wv * ao[sg*6+r][e];
        }
        #pragma unroll
        for (int r = 0; r < 6; r++) { int s = sg*6+r; t2[s][o] = acc[r] + hs[s][o]; }
    }
    __syncthreads();
    ln_write(t2, lg, lb, hp, t);
}

// ---------------- fused: enc conv + cross-attention (2 encoders, avg) + LN ----------------
// encx: [C][BN][S][E]; ckw: ckT + l*C*3*E*E ([i][k][e][o]); ckb: conv_k_b + l*C*E ([i][E])
// w: ca_w[l] = [C][4][E][E]; b: ca_b[l] = [C][4][E]
__global__ void __launch_bounds__(256)
k_crossattn(float* h, const float* __restrict__ encx,
            const float* __restrict__ ckw, const float* __restrict__ ckb,
            const float* __restrict__ w, const float* __restrict__ b,
            const float* __restrict__ lg, const float* __restrict__ lb) {
    __shared__ float hs[S_][E_];
    __shared__ float eraw[S_][E_];
    __shared__ float es[S_][E_];
    __shared__ float qkv[3][S_][E_+1];
    __shared__ float ao[S_][E_+1];
    __shared__ float t2[S_][E_];
    int bn = blockIdx.x, t = threadIdx.x;
    float* hp = h + (size_t)bn * (S_*E_);
    for (int i = t; i < S_*E_; i += 256) hs[i>>7][i&(E_-1)] = hp[i];
    const int o = t & (E_-1), sg = t >> 7;
    float creg[6];
    #pragma unroll
    for (int r = 0; r < 6; r++) creg[r] = 0.f;
    for (int ci = 0; ci < C_; ci++) {
        const float* ep = encx + ((size_t)ci*BN_ + bn) * (S_*E_);
        __syncthreads();                   // hs ready (ci=0) / prev-iter reads done
        for (int i = t; i < S_*E_; i += 256) eraw[i>>7][i&(E_-1)] = ep[i];
        __syncthreads();
        {   // conv1d k=3 pad=1 with bias
            const float* wct = ckw + ci*3*E_*E_;
            float acc[6];
            float bv = ckb[ci*E_ + o];
            #pragma unroll
            for (int r = 0; r < 6; r++) acc[r] = bv;
            for (int e = 0; e < E_; e++) {
                float w0 = wct[e*E_ + o];
                float w1 = wct[(E_ + e)*E_ + o];
                float w2 = wct[(2*E_ + e)*E_ + o];
                #pragma unroll
                for (int r = 0; r < 6; r++) {
                    int s = sg*6 + r;
                    if (s >= 1)     acc[r] += w0 * eraw[s-1][e];
                    acc[r] += w1 * eraw[s][e];
                    if (s < S_-1)   acc[r] += w2 * eraw[s+1][e];
                }
            }
            #pragma unroll
            for (int r = 0; r < 6; r++) es[sg*6+r][o] = acc[r];
        }
        __syncthreads();
        for (int j = 0; j < 3; j++) {      // q from hs; k,v from es
            const float* wj = w + (ci*4 + j)*E_*E_;
            float bj = b[(ci*4 + j)*E_ + o];
            float acc[6];
            #pragma unroll
            for (int r = 0; r < 6; r++) acc[r] = bj;
            const float (*src)[E_] = (j == 0) ? hs : es;
            for (int e = 0; e < E_; e++) {
                float wv = wj[e*E_ + o];
                #pragma unroll
                for (int r = 0; r < 6; r++) acc[r] += wv * src[sg*6+r][e];
            }
            #pragma unroll
            for (int r = 0; r < 6; r++) qkv[j][sg*6+r][o] = acc[r];
        }
        __syncthreads();
        if (t < H_*S_) {                   // no mask
            int qi = t % S_, hh = t / S_, hb = hh*DH_;
            float sc[S_], mx = -1e30f;
            #pragma unroll
            for (int j = 0; j < S_; j++) {
                float s = 0.f;
                #pragma unroll
                for (int d = 0; d < DH_; d++) s += qkv[0][qi][hb+d] * qkv[1][j][hb+d];
                s *= 0.25f;
                sc[j] = s; mx = fmaxf(mx, s);
            }
            float sum = 0.f;
            #pragma unroll
            for (int j = 0; j < S_; j++) { sc[j] = expf(sc[j]-mx); sum += sc[j]; }
            float inv = 1.f / sum;
            #pragma unroll
            for (int d = 0; d < DH_; d++) {
                float ov = 0.f;
                #pragma unroll
                for (int j = 0; j < S_; j++) ov += sc[j] * qkv[2][j][hb+d];
                ao[qi][hb+d] = ov * inv;
            }
        }
        __syncthreads();
        {
            const float* w3 = w + (ci*4 + 3)*E_*E_;
            float b3 = b[(ci*4 + 3)*E_ + o];
            float acc[6];
            #pragma unroll
            for (int r = 0; r < 6; r++) acc[r] = b3;
            for (int e = 0; e < E_; e++) {
                float wv = w3[e*E_ + o];
                #pragma unroll
                for (int r = 0; r < 6; r++) acc[r] += wv * ao[sg*6+r][e];
            }
            #pragma unroll
            for (int r = 0; r < 6; r++) creg[r] += acc[r];
        }
    }
    #pragma unroll
    for (int r = 0; r < 6; r++) { int s = sg*6+r; t2[s][o] = hs[s][o] + 0.5f*creg[r]; }
    __syncthreads();
    ln_write(t2, lg, lb, hp, t);
}

// ---------------- FFN + residual + LN ----------------
__global__ void __launch_bounds__(256)
k_ffn(float* h, const float* __restrict__ w1, const float* __restrict__ b1,
      const float* __restrict__ w2, const float* __restrict__ b2,
      const float* __restrict__ lg, const float* __restrict__ lb) {
    __shared__ float hs[S_][E_];
    __shared__ float mid[S_][FF_];
    __shared__ float t2[S_][E_];
    int bn = blockIdx.x, t = threadIdx.x;
    float* hp = h + (size_t)bn * (S_*E_);
    for (int i = t; i < S_*E_; i += 256) hs[i>>7][i&(E_-1)] = hp[i];
    __syncthreads();
    for (int oc = 0; oc < 2; oc++) {       // each thread: 2 columns x 12 rows
        int o2 = t + oc*256;
        float acc[S_];
        float bv = b1[o2];
        #pragma unroll
        for (int s = 0; s < S_; s++) acc[s] = bv;
        for (int e = 0; e < E_; e++) {
            float wv = w1[e*FF_ + o2];
            #pragma unroll
            for (int s = 0; s < S_; s++) acc[s] += wv * hs[s][e];
        }
        #pragma unroll
        for (int s = 0; s < S_; s++) mid[s][o2] = fmaxf(acc[s], 0.f);
    }
    __syncthreads();
    const int o = t & (E_-1), sg = t >> 7;
    {
        float bv = b2[o];
        float acc[6];
        #pragma unroll
        for (int r = 0; r < 6; r++) acc[r] = bv;
        for (int e = 0; e < FF_; e++) {
            float wv = w2[e*E_ + o];
            #pragma unroll
            for (int r = 0; r < 6; r++) acc[r] += wv * mid[sg*6+r][e];
        }
        #pragma unroll
        for (int r = 0; r < 6; r++) { int s = sg*6+r; t2[s][o] = hs[s][o] + acc[r]; }
    }
    __syncthreads();
    ln_write(t2, lg, lb, hp, t);
}

// ---------------- final projection to OUT=1 + output transpose ----------------
__global__ void k_final(const float* __restrict__ h, const float* __restrict__ fc_w,
                        const float* __restrict__ fc_b, float* __restrict__ out) {
    int gid  = blockIdx.x * 256 + threadIdx.x;
    int tok  = gid >> 6;                  // bn*S_ + s
    int lane = gid & 63;
    if (tok >= BN_*S_) return;
    const float* hp = h + (size_t)tok * E_;
    float v = hp[lane]*fc_w[lane] + hp[lane+64]*fc_w[lane+64];
    #pragma unroll
    for (int off = 32; off; off >>= 1) v += __shfl_xor(v, off);
    if (lane == 0) {
        int bn = tok / S_, s = tok % S_;
        int b = bn / N_, n = bn % N_;
        out[(b*S_ + s)*N_ + n] = v + fc_b[0];
    }
}

extern "C" void kernel_launch(void* const* d_in, const int* in_sizes, int n_in,
                              void* d_out, int out_size, void* d_ws, size_t ws_size,
                              hipStream_t stream) {
    const float* x        = (const float*)d_in[0];
    const float* enc_x    = (const float*)d_in[1];
    // d_in[2] = tgt_mask (tril ones) — causality hardcoded
    const float* emb_w    = (const float*)d_in[3];
    const float* emb_b    = (const float*)d_in[4];
    const float* pe       = (const float*)d_in[5];
    const float* conv_q_w = (const float*)d_in[6];
    const float* conv_k_w = (const float*)d_in[7];
    const float* conv_k_b = (const float*)d_in[8];
    const float* sa_w     = (const float*)d_in[9];
    const float* sa_b     = (const float*)d_in[10];
    const float* ca_w     = (const float*)d_in[11];
    const float* ca_b     = (const float*)d_in[12];
    const float* ff_w1    = (const float*)d_in[13];
    const float* ff_b1    = (const float*)d_in[14];
    const float* ff_w2    = (const float*)d_in[15];
    const float* ff_b2    = (const float*)d_in[16];
    const float* ln_g     = (const float*)d_in[17];
    const float* ln_b     = (const float*)d_in[18];
    const float* fc_w     = (const float*)d_in[19];
    const float* fc_b     = (const float*)d_in[20];

    const size_t HN = (size_t)BN_ * S_ * E_;   // 16,711,680 floats
    float* ws   = (float*)d_ws;
    float* h    = ws;                           // HN floats (~67 MB)
    float* cqT  = ws + HN;                      // L*2*E*E
    float* ckT  = cqT + L_*2*E_*E_;             // L*C*3*E*E

    k_embed<<<(BN_*S_*E_)/256, 256, 0, stream>>>(x, emb_w, emb_b, pe, h);
    {
        int wtot = L_*2*E_*E_ + L_*C_*3*E_*E_;  // 524288 = 2048*256
        k_wtrans<<<wtot/256, 256, 0, stream>>>(conv_q_w, conv_k_w, cqT, ckT);
    }
    for (int l = 0; l < L_; l++) {
        k_selfattn<<<BN_, 256, 0, stream>>>(
            h, cqT + (size_t)l*2*E_*E_,
            sa_w + (size_t)l*4*E_*E_, sa_b + l*4*E_,
            ln_g + (l*3 + 0)*E_, ln_b + (l*3 + 0)*E_);
        k_crossattn<<<BN_, 256, 0, stream>>>(
            h, enc_x,
            ckT + (size_t)l*C_*3*E_*E_, conv_k_b + l*C_*E_,
            ca_w + (size_t)l*C_*4*E_*E_, ca_b + l*C_*4*E_,
            ln_g + (l*3 + 1)*E_, ln_b + (l*3 + 1)*E_);
        k_ffn<<<BN_, 256, 0, stream>>>(
            h, ff_w1 + (size_t)l*E_*FF_, ff_b1 + l*FF_,
            ff_w2 + (size_t)l*FF_*E_, ff_b2 + l*E_,
            ln_g + (l*3 + 2)*E_, ln_b + (l*3 + 2)*E_);
    }
    k_final<<<(BN_*S_*64)/256, 256, 0, stream>>>(h, fc_w, fc_b, (float*)d_out);
}

// Round 3
// 2722.652 us; speedup vs baseline: 5.8760x; 5.8760x over previous
//
#include <hip/hip_runtime.h>

// f32 storage everywhere; bf16 only as MFMA matmul inputs (f32 accumulate).

#define B_   64
#define S_   12
#define N_   170
#define BN_  (B_*N_)      // 10880
#define E_   128
#define L_   4
#define C_   2
#define H_   8
#define DH_  16
#define FF_  512
#define EPS_ 1e-5f

typedef unsigned short u16;
typedef __attribute__((ext_vector_type(4))) float f32x4;
typedef __attribute__((ext_vector_type(8))) u16   us8;
typedef __attribute__((ext_vector_type(4))) u16   us4;
typedef __attribute__((ext_vector_type(8))) __bf16 bf16x8;
union FragU { us8 u; bf16x8 b; };

__device__ __forceinline__ u16 f2bf(float f) {            // RNE f32->bf16
    unsigned u = __builtin_bit_cast(unsigned, f);
    u += 0x7fff + ((u >> 16) & 1);
    return (u16)(u >> 16);
}
__device__ __forceinline__ float bf2f(u16 s) {
    return __builtin_bit_cast(float, (unsigned)s << 16);
}

// ---------------- embed + positional encoding ----------------
__global__ void k_embed(const float* __restrict__ x, const float* __restrict__ emb_w,
                        const float* __restrict__ emb_b, const float* __restrict__ pe,
                        float* __restrict__ h) {
    int idx = blockIdx.x * 256 + threadIdx.x;
    int e  = idx & (E_-1);
    int se = idx >> 7;
    int s  = se % S_;
    int bn = se / S_;
    int b = bn / N_, n = bn % N_;
    h[idx] = x[(b*S_ + s)*N_ + n] * emb_w[e] + emb_b[e] + pe[s*E_ + e];
}

// ---------------- weight pre-pack into MFMA B-fragment order ----------------
// Per pass (W[K][O]): packed[((ntile*KS+ks)*64+lane)*8+i] = bf16(W[ks*32+(lane>>4)*8+i][ntile*16+(lane&15)])
// Layer layout (u16 elems): cq taps 2x16384 @0 | sa 4x16384 @32768 | ck 6x16384 @98304
//                           | ca 8x16384 @196608 | ff1 @327680 | ff2 @393216 ; layer stride 458752
__global__ void k_wpack(const float* __restrict__ cq, const float* __restrict__ sa,
                        const float* __restrict__ ck, const float* __restrict__ ca,
                        const float* __restrict__ f1, const float* __restrict__ f2,
                        u16* __restrict__ wp) {
    int f  = blockIdx.x * 256 + threadIdx.x;    // frag id, total 229376
    int l  = f / 57344, fl = f % 57344;
    const float* src; int sk, so, KS, q;
    if (fl < 4096)        { int tap = fl >> 11; q = fl & 2047; KS = 4;
                            src = cq + (size_t)l*49152 + tap;            sk = 3;   so = 384; }
    else if (fl < 12288)  { int j = (fl - 4096) >> 11; q = fl & 2047; KS = 4;
                            src = sa + (size_t)(l*4 + j)*16384;          sk = 128; so = 1;   }
    else if (fl < 24576)  { int ct = (fl - 12288) >> 11; q = fl & 2047; KS = 4;
                            int ci = ct / 3, tap = ct % 3;
                            src = ck + (size_t)(l*2 + ci)*49152 + tap;   sk = 3;   so = 384; }
    else if (fl < 40960)  { int cj = (fl - 24576) >> 11; q = fl & 2047; KS = 4;
                            src = ca + (size_t)(l*8 + cj)*16384;         sk = 128; so = 1;   }
    else if (fl < 49152)  { q = fl - 40960; KS = 4;
                            src = f1 + (size_t)l*65536;                  sk = 512; so = 1;   }
    else                  { q = fl - 49152; KS = 16;
                            src = f2 + (size_t)l*65536;                  sk = 128; so = 1;   }
    int lane = q & 63, tt = q >> 6;
    int ks = tt % KS, ntile = tt / KS;
    int k0 = ks*32 + ((lane >> 4) << 3);
    int o  = ntile*16 + (lane & 15);
    us8 w;
    #pragma unroll
    for (int i = 0; i < 8; i++) w[i] = f2bf(src[(size_t)(k0 + i)*sk + (size_t)o*so]);
    *(us8*)(wp + (size_t)f*8) = w;
}

// ---------------- shared device helpers ----------------
// Stage 48x128 f32 -> swizzled bf16 LDS (256B rows, byte ^= (row&7)<<4)
__device__ __forceinline__ void stage48(const float* __restrict__ src, u16* dst, int t) {
    for (int i = t; i < 1536; i += 256) {
        const float4 v = ((const float4*)src)[i];
        int elem = i << 2;
        int row = elem >> 7, colb = (elem & 127) << 1;
        us4 w; w[0] = f2bf(v.x); w[1] = f2bf(v.y); w[2] = f2bf(v.z); w[3] = f2bf(v.w);
        *(us4*)((char*)dst + (((row << 8) + colb) ^ ((row & 7) << 4))) = w;
    }
}

template<int NTW>
__device__ __forceinline__ void acc_init(f32x4 (&acc)[3][NTW], const float* bias, int wave, int lane) {
    #pragma unroll
    for (int nl = 0; nl < NTW; nl++) {
        float bv = bias ? bias[(wave*NTW + nl)*16 + (lane & 15)] : 0.f;
        #pragma unroll
        for (int mt = 0; mt < 3; mt++) {
            acc[mt][nl][0] = bv; acc[mt][nl][1] = bv; acc[mt][nl][2] = bv; acc[mt][nl][3] = bv;
        }
    }
}

// GEMM: D[48][O] += A[48][K] * Wpacked ; A in swizzled bf16 LDS, ROWB = row bytes
template<int NTW, int KS, int ROWB>
__device__ __forceinline__ void gemm48(const u16* A, const us8* __restrict__ WP,
                                       f32x4 (&acc)[3][NTW], int wave, int lane) {
    #pragma unroll
    for (int ks = 0; ks < KS; ks++) {
        bf16x8 a[3];
        #pragma unroll
        for (int mt = 0; mt < 3; mt++) {
            int row  = mt*16 + (lane & 15);
            int colb = (ks*32 + ((lane >> 4) << 3)) << 1;
            FragU fu; fu.u = *(const us8*)((const char*)A + ((row*ROWB + colb) ^ ((row & 7) << 4)));
            a[mt] = fu.b;
        }
        #pragma unroll
        for (int nl = 0; nl < NTW; nl++) {
            FragU fb; fb.u = WP[((wave*NTW + nl)*KS + ks)*64 + lane];
            #pragma unroll
            for (int mt = 0; mt < 3; mt++)
                acc[mt][nl] = __builtin_amdgcn_mfma_f32_16x16x32_bf16(a[mt], fb.b, acc[mt][nl], 0, 0, 0);
        }
    }
}

// GEMM with per-mtile source rows (conv taps; sr<0 -> zero row)
template<int NTW>
__device__ __forceinline__ void gemm48_rows(const u16* A, const u16* ZR, const int (&sr)[3],
                                            const us8* __restrict__ WP,
                                            f32x4 (&acc)[3][NTW], int wave, int lane) {
    #pragma unroll
    for (int ks = 0; ks < 4; ks++) {
        bf16x8 a[3];
        #pragma unroll
        for (int mt = 0; mt < 3; mt++) {
            int colb = (ks*32 + ((lane >> 4) << 3)) << 1;
            const char* p = (sr[mt] >= 0)
                ? (const char*)A + (((sr[mt] << 8) + colb) ^ ((sr[mt] & 7) << 4))
                : (const char*)ZR + colb;
            FragU fu; fu.u = *(const us8*)p;
            a[mt] = fu.b;
        }
        #pragma unroll
        for (int nl = 0; nl < NTW; nl++) {
            FragU fb; fb.u = WP[((wave*NTW + nl)*4 + ks)*64 + lane];
            #pragma unroll
            for (int mt = 0; mt < 3; mt++)
                acc[mt][nl] = __builtin_amdgcn_mfma_f32_16x16x32_bf16(a[mt], fb.b, acc[mt][nl], 0, 0, 0);
        }
    }
}

// acc (D layout: row=mt*16+(lane>>4)*4+r, col=nt*16+(lane&15)) -> swizzled bf16 LDS
template<int NTW, int ROWB, bool RELU>
__device__ __forceinline__ void acc_store_bf(const f32x4 (&acc)[3][NTW], u16* B, int wave, int lane) {
    #pragma unroll
    for (int mt = 0; mt < 3; mt++)
    #pragma unroll
    for (int nl = 0; nl < NTW; nl++)
    #pragma unroll
    for (int r = 0; r < 4; r++) {
        int row = mt*16 + ((lane >> 4) << 2) + r;
        int col = (wave*NTW + nl)*16 + (lane & 15);
        float v = acc[mt][nl][r];
        if (RELU) v = fmaxf(v, 0.f);
        *(u16*)((char*)B + ((row*ROWB + (col << 1)) ^ ((row & 7) << 4))) = f2bf(v);
    }
}

template<int NTW>
__device__ __forceinline__ void t2_from_regs(const f32x4 (&acc)[3][NTW], const f32x4 (&res)[3][NTW],
                                             float* T2, int wave, int lane) {
    #pragma unroll
    for (int mt = 0; mt < 3; mt++)
    #pragma unroll
    for (int nl = 0; nl < NTW; nl++)
    #pragma unroll
    for (int r = 0; r < 4; r++) {
        int row = mt*16 + ((lane >> 4) << 2) + r;
        int col = (wave*NTW + nl)*16 + (lane & 15);
        T2[row*128 + col] = acc[mt][nl][r] + res[mt][nl][r];
    }
}

template<int NTW>
__device__ __forceinline__ void t2_res_global(const f32x4 (&acc)[3][NTW], const float* __restrict__ hres,
                                              float scale, float* T2, int wave, int lane) {
    #pragma unroll
    for (int mt = 0; mt < 3; mt++)
    #pragma unroll
    for (int nl = 0; nl < NTW; nl++)
    #pragma unroll
    for (int r = 0; r < 4; r++) {
        int row = mt*16 + ((lane >> 4) << 2) + r;
        int col = (wave*NTW + nl)*16 + (lane & 15);
        T2[row*128 + col] = hres[row*128 + col] + scale*acc[mt][nl][r];
    }
}

__device__ __forceinline__ void ld16(const u16* Bf, int row, int colb, float* o16) {
    int x = (row & 7) << 4;
    int base = (row << 8) + colb;
    us8 u0 = *(const us8*)((const char*)Bf + (base ^ x));
    us8 u1 = *(const us8*)((const char*)Bf + ((base + 16) ^ x));
    #pragma unroll
    for (int d = 0; d < 8; d++) { o16[d] = bf2f(u0[d]); o16[8+d] = bf2f(u1[d]); }
}

// 384 tasks = 4bn x 8heads x 12 qrows; q (in QA) replaced in place by attention output
template<bool MASK>
__device__ __forceinline__ void attn48(u16* QA, const u16* KB, const u16* VB, int t) {
    #pragma unroll
    for (int it = 0; it < 2; it++) {
        int task = t + it*256;
        if (task < 384) {
            int g = task / 96, rem = task % 96;
            int hh = rem / 12, qi = rem % 12;
            int hb2 = hh << 5;
            int rq = g*12 + qi;
            float qv[16]; ld16(QA, rq, hb2, qv);
            float sc[12]; float mx = -1e30f;
            #pragma unroll
            for (int j = 0; j < 12; j++) {
                float kv[16]; ld16(KB, g*12 + j, hb2, kv);
                float s = 0.f;
                #pragma unroll
                for (int d = 0; d < 16; d++) s += qv[d]*kv[d];
                s *= 0.25f;
                if (MASK && j > qi) s = -1e30f;
                sc[j] = s; mx = fmaxf(mx, s);
            }
            float sum = 0.f;
            #pragma unroll
            for (int j = 0; j < 12; j++) { sc[j] = expf(sc[j] - mx); sum += sc[j]; }
            float inv = 1.f/sum;
            float ov[16];
            #pragma unroll
            for (int d = 0; d < 16; d++) ov[d] = 0.f;
            #pragma unroll
            for (int j = 0; j < 12; j++) {
                float vv[16]; ld16(VB, g*12 + j, hb2, vv);
                #pragma unroll
                for (int d = 0; d < 16; d++) ov[d] += sc[j]*vv[d];
            }
            int x = (rq & 7) << 4;
            us8 w0, w1;
            #pragma unroll
            for (int d = 0; d < 8; d++) { w0[d] = f2bf(ov[d]*inv); w1[d] = f2bf(ov[8+d]*inv); }
            *(us8*)((char*)QA + (((rq << 8) + hb2) ^ x))      = w0;
            *(us8*)((char*)QA + (((rq << 8) + hb2 + 16) ^ x)) = w1;
        }
    }
}

// per-wave LN of 12 rows from T2 f32 -> global
__device__ __forceinline__ void ln48(const float* T2, const float* __restrict__ g,
                                     const float* __restrict__ b, float* __restrict__ outp,
                                     int wave, int lane) {
    #pragma unroll
    for (int i = 0; i < 12; i++) {
        int r = wave*12 + i;
        float x0 = T2[r*128 + lane], x1 = T2[r*128 + lane + 64];
        float s = x0 + x1;
        #pragma unroll
        for (int off = 32; off; off >>= 1) s += __shfl_xor(s, off);
        float m = s * (1.f/E_);
        float d0 = x0 - m, d1 = x1 - m;
        float s2 = d0*d0 + d1*d1;
        #pragma unroll
        for (int off = 32; off; off >>= 1) s2 += __shfl_xor(s2, off);
        float inv = rsqrtf(s2 * (1.f/E_) + EPS_);
        outp[r*128 + lane]      = d0*inv*g[lane]      + b[lane];
        outp[r*128 + lane + 64] = d1*inv*g[lane + 64] + b[lane + 64];
    }
}

// ---------------- fused: masked conv + self-attn + residual + LN (4 bn / block) ----------------
__global__ void __launch_bounds__(256)
k_selfattn(float* __restrict__ h, const u16* __restrict__ lw /* cq@0, sa@32768 */,
           const float* __restrict__ sab, const float* __restrict__ lg, const float* __restrict__ lb) {
    __shared__ __align__(16) u16 sm[5*6144 + 128];
    u16* AX = sm;              // h bf16 (conv input)
    u16* CX = sm + 6144;       // conv out bf16
    u16* QB = sm + 12288;      // q -> ao (in place)
    u16* KB = sm + 18432;
    u16* VB = sm + 24576;
    u16* ZR = sm + 30720;
    float* T2 = (float*)(sm + 12288);   // overlays QB+KB after attention

    int t = threadIdx.x, wave = t >> 6, lane = t & 63;
    float* hp = h + (size_t)blockIdx.x * (48*128);
    if (t < 64) ((unsigned*)ZR)[t] = 0;
    stage48(hp, AX, t);
    __syncthreads();

    int gg[3], rr[3];
    #pragma unroll
    for (int mt = 0; mt < 3; mt++) { int m = mt*16 + (lane & 15); gg[mt] = m/12; rr[mt] = m - gg[mt]*12; }

    f32x4 cacc[3][2];
    acc_init<2>(cacc, nullptr, wave, lane);
    {   // causal conv: tap0 -> row-1, tap1 -> row
        int sr[3];
        #pragma unroll
        for (int mt = 0; mt < 3; mt++) { int r2 = rr[mt] - 1; sr[mt] = (r2 >= 0) ? gg[mt]*12 + r2 : -1; }
        gemm48_rows<2>(AX, ZR, sr, (const us8*)lw, cacc, wave, lane);
        #pragma unroll
        for (int mt = 0; mt < 3; mt++) sr[mt] = gg[mt]*12 + rr[mt];
        gemm48_rows<2>(AX, ZR, sr, (const us8*)(lw + 16384), cacc, wave, lane);
    }
    acc_store_bf<2,256,false>(cacc, CX, wave, lane);
    __syncthreads();

    {   // QKV projections from conv output
        f32x4 acc[3][2];
        const u16* sap = lw + 32768;
        acc_init<2>(acc, sab,          wave, lane);
        gemm48<2,4,256>(CX, (const us8*)sap,            acc, wave, lane);
        acc_store_bf<2,256,false>(acc, QB, wave, lane);
        acc_init<2>(acc, sab + 128,    wave, lane);
        gemm48<2,4,256>(CX, (const us8*)(sap + 16384),  acc, wave, lane);
        acc_store_bf<2,256,false>(acc, KB, wave, lane);
        acc_init<2>(acc, sab + 256,    wave, lane);
        gemm48<2,4,256>(CX, (const us8*)(sap + 32768),  acc, wave, lane);
        acc_store_bf<2,256,false>(acc, VB, wave, lane);
    }
    __syncthreads();
    attn48<true>(QB, KB, VB, t);
    __syncthreads();
    {   // out-proj + residual (conv regs) + LN
        f32x4 acc[3][2];
        acc_init<2>(acc, sab + 384, wave, lane);
        gemm48<2,4,256>(QB, (const us8*)(lw + 32768 + 3*16384), acc, wave, lane);
        __syncthreads();                       // all QB/KB reads done before T2 overlay write
        t2_from_regs<2>(acc, cacc, T2, wave, lane);
    }
    __syncthreads();
    ln48(T2, lg, lb, hp, wave, lane);
}

// ---------------- fused: enc conv + cross-attn (2 encoders, avg) + residual + LN ----------------
__global__ void __launch_bounds__(256)
k_crossattn(float* __restrict__ h, const float* __restrict__ encx,
            const u16* __restrict__ ckp, const u16* __restrict__ cap,
            const float* __restrict__ ckb, const float* __restrict__ cab,
            const float* __restrict__ lg, const float* __restrict__ lb) {
    __shared__ __align__(16) u16 sm[5*6144 + 128];
    u16* HX = sm;              // h bf16 (Q input, both ci)
    u16* S1 = sm + 6144;       // eraw -> V
    u16* ES = sm + 12288;      // conv out
    u16* QA = sm + 18432;      // q -> ao
    u16* KK = sm + 24576;
    u16* ZR = sm + 30720;
    float* T2 = (float*)(sm + 6144);    // overlays S1+ES at the end

    int t = threadIdx.x, wave = t >> 6, lane = t & 63;
    float* hp = h + (size_t)blockIdx.x * (48*128);
    if (t < 64) ((unsigned*)ZR)[t] = 0;
    stage48(hp, HX, t);

    int gg[3], rr[3];
    #pragma unroll
    for (int mt = 0; mt < 3; mt++) { int m = mt*16 + (lane & 15); gg[mt] = m/12; rr[mt] = m - gg[mt]*12; }

    f32x4 creg[3][2];
    #pragma unroll
    for (int nl = 0; nl < 2; nl++) {    // init with bo(ci=0)+bo(ci=1)
        int col = (wave*2 + nl)*16 + (lane & 15);
        float bv = cab[3*128 + col] + cab[7*128 + col];
        #pragma unroll
        for (int mt = 0; mt < 3; mt++) { creg[mt][nl][0]=bv; creg[mt][nl][1]=bv; creg[mt][nl][2]=bv; creg[mt][nl][3]=bv; }
    }

    for (int ci = 0; ci < C_; ci++) {
        __syncthreads();
        stage48(encx + ((size_t)ci*BN_ + (size_t)blockIdx.x*4) * (S_*E_), S1, t);
        __syncthreads();
        f32x4 acc[3][2];
        acc_init<2>(acc, ckb + ci*128, wave, lane);
        #pragma unroll
        for (int tap = 0; tap < 3; tap++) {
            int sr[3];
            #pragma unroll
            for (int mt = 0; mt < 3; mt++) {
                int r2 = rr[mt] + tap - 1;
                sr[mt] = (r2 >= 0 && r2 < 12) ? gg[mt]*12 + r2 : -1;
            }
            gemm48_rows<2>(S1, ZR, sr, (const us8*)(ckp + (ci*3 + tap)*16384), acc, wave, lane);
        }
        acc_store_bf<2,256,false>(acc, ES, wave, lane);
        __syncthreads();
        acc_init<2>(acc, cab + (ci*4 + 0)*128, wave, lane);
        gemm48<2,4,256>(HX, (const us8*)(cap + (ci*4 + 0)*16384), acc, wave, lane);
        acc_store_bf<2,256,false>(acc, QA, wave, lane);
        acc_init<2>(acc, cab + (ci*4 + 1)*128, wave, lane);
        gemm48<2,4,256>(ES, (const us8*)(cap + (ci*4 + 1)*16384), acc, wave, lane);
        acc_store_bf<2,256,false>(acc, KK, wave, lane);
        acc_init<2>(acc, cab + (ci*4 + 2)*128, wave, lane);
        gemm48<2,4,256>(ES, (const us8*)(cap + (ci*4 + 2)*16384), acc, wave, lane);
        acc_store_bf<2,256,false>(acc, S1, wave, lane);     // V over eraw
        __syncthreads();
        attn48<false>(QA, KK, S1, t);
        __syncthreads();
        gemm48<2,4,256>(QA, (const us8*)(cap + (ci*4 + 3)*16384), creg, wave, lane);
    }
    __syncthreads();                         // QA reads done; S1/ES free for T2
    t2_res_global<2>(creg, hp, 0.5f, T2, wave, lane);
    __syncthreads();
    ln48(T2, lg, lb, hp, wave, lane);
}

// ---------------- FFN + residual + LN ----------------
__global__ void __launch_bounds__(256)
k_ffn(float* __restrict__ h, const u16* __restrict__ f1p, const float* __restrict__ fb1,
      const u16* __restrict__ f2p, const float* __restrict__ fb2,
      const float* __restrict__ lg, const float* __restrict__ lb) {
    __shared__ __align__(16) u16 sm[6144 + 24576];
    u16* XH  = sm;                     // h bf16
    u16* MID = sm + 6144;              // relu(h W1 + b1) bf16, rows of 1024B
    float* T2 = (float*)sm;            // overlays XH + MID rows 0..11 at the end

    int t = threadIdx.x, wave = t >> 6, lane = t & 63;
    float* hp = h + (size_t)blockIdx.x * (48*128);
    stage48(hp, XH, t);
    __syncthreads();

    {
        f32x4 acc1[3][8];
        acc_init<8>(acc1, fb1, wave, lane);
        gemm48<8,4,256>(XH, (const us8*)f1p, acc1, wave, lane);
        acc_store_bf<8,1024,true>(acc1, MID, wave, lane);
    }
    __syncthreads();
    {
        f32x4 acc2[3][2];
        acc_init<2>(acc2, fb2, wave, lane);
        gemm48<2,16,1024>(MID, (const us8*)f2p, acc2, wave, lane);
        __syncthreads();                // all MID reads done before T2 overlay write
        t2_res_global<2>(acc2, hp, 1.0f, T2, wave, lane);
    }
    __syncthreads();
    ln48(T2, lg, lb, hp, wave, lane);
}

// ---------------- final projection to OUT=1 + output transpose ----------------
__global__ void k_final(const float* __restrict__ h, const float* __restrict__ fc_w,
                        const float* __restrict__ fc_b, float* __restrict__ out) {
    int gid  = blockIdx.x * 256 + threadIdx.x;
    int tok  = gid >> 6;
    int lane = gid & 63;
    if (tok >= BN_*S_) return;
    const float* hp = h + (size_t)tok * E_;
    float v = hp[lane]*fc_w[lane] + hp[lane+64]*fc_w[lane+64];
    #pragma unroll
    for (int off = 32; off; off >>= 1) v += __shfl_xor(v, off);
    if (lane == 0) {
        int bn = tok / S_, s = tok % S_;
        int b = bn / N_, n = bn % N_;
        out[(b*S_ + s)*N_ + n] = v + fc_b[0];
    }
}

extern "C" void kernel_launch(void* const* d_in, const int* in_sizes, int n_in,
                              void* d_out, int out_size, void* d_ws, size_t ws_size,
                              hipStream_t stream) {
    const float* x        = (const float*)d_in[0];
    const float* enc_x    = (const float*)d_in[1];
    const float* emb_w    = (const float*)d_in[3];
    const float* emb_b    = (const float*)d_in[4];
    const float* pe       = (const float*)d_in[5];
    const float* conv_q_w = (const float*)d_in[6];
    const float* conv_k_w = (const float*)d_in[7];
    const float* conv_k_b = (const float*)d_in[8];
    const float* sa_w     = (const float*)d_in[9];
    const float* sa_b     = (const float*)d_in[10];
    const float* ca_w     = (const float*)d_in[11];
    const float* ca_b     = (const float*)d_in[12];
    const float* ff_w1    = (const float*)d_in[13];
    const float* ff_b1    = (const float*)d_in[14];
    const float* ff_w2    = (const float*)d_in[15];
    const float* ff_b2    = (const float*)d_in[16];
    const float* ln_g     = (const float*)d_in[17];
    const float* ln_b     = (const float*)d_in[18];
    const float* fc_w     = (const float*)d_in[19];
    const float* fc_b     = (const float*)d_in[20];

    const size_t HN = (size_t)BN_ * S_ * E_;   // 16,711,680 floats
    float* h  = (float*)d_ws;
    u16* wpk  = (u16*)((float*)d_ws + HN);     // 1,835,008 u16 (3.7 MB)

    k_embed<<<(BN_*S_*E_)/256, 256, 0, stream>>>(x, emb_w, emb_b, pe, h);
    k_wpack<<<896, 256, 0, stream>>>(conv_q_w, sa_w, conv_k_w, ca_w, ff_w1, ff_w2, wpk);

    for (int l = 0; l < L_; l++) {
        const u16* lw = wpk + (size_t)l*458752;
        k_selfattn<<<BN_/4, 256, 0, stream>>>(
            h, lw, sa_b + l*512,
            ln_g + (l*3 + 0)*E_, ln_b + (l*3 + 0)*E_);
        k_crossattn<<<BN_/4, 256, 0, stream>>>(
            h, enc_x, lw + 98304, lw + 196608,
            conv_k_b + l*256, ca_b + l*1024,
            ln_g + (l*3 + 1)*E_, ln_b + (l*3 + 1)*E_);
        k_ffn<<<BN_/4, 256, 0, stream>>>(
            h, lw + 327680, ff_b1 + l*512, lw + 393216, ff_b2 + l*128,
            ln_g + (l*3 + 2)*E_, ln_b + (l*3 + 2)*E_);
    }
    k_final<<<(BN_*S_*64)/256, 256, 0, stream>>>(h, fc_w, fc_b, (float*)d_out);
}

// Round 4
// 2064.869 us; speedup vs baseline: 7.7478x; 1.3186x over previous
//
#include <hip/hip_runtime.h>

// f32 storage; bf16 only as MFMA inputs (f32 accumulate). One fused kernel per layer.

#define B_   64
#define S_   12
#define N_   170
#define BN_  (B_*N_)      // 10880
#define E_   128
#define L_   4
#define C_   2
#define H_   8
#define DH_  16
#define FF_  512
#define EPS_ 1e-5f

typedef unsigned short u16;
typedef __attribute__((ext_vector_type(4))) float f32x4;
typedef __attribute__((ext_vector_type(8))) u16   us8;
typedef __attribute__((ext_vector_type(4))) u16   us4;
typedef __attribute__((ext_vector_type(8))) __bf16 bf16x8;
union FragU { us8 u; bf16x8 b; };

__device__ __forceinline__ u16 f2bf(float f) {            // RNE f32->bf16
    unsigned u = __builtin_bit_cast(unsigned, f);
    u += 0x7fff + ((u >> 16) & 1);
    return (u16)(u >> 16);
}
__device__ __forceinline__ float bf2f(u16 s) {
    return __builtin_bit_cast(float, (unsigned)s << 16);
}

// ---------------- weight pre-pack into MFMA B-fragment order (unchanged layout) ----------------
// Layer layout (u16): cq 2x16384 @0 | sa 4x16384 @32768 | ck 6x16384 @98304
//                     | ca 8x16384 @196608 | ff1 @327680 | ff2 @393216 ; stride 458752
__global__ void k_wpack(const float* __restrict__ cq, const float* __restrict__ sa,
                        const float* __restrict__ ck, const float* __restrict__ ca,
                        const float* __restrict__ f1, const float* __restrict__ f2,
                        u16* __restrict__ wp) {
    int f  = blockIdx.x * 256 + threadIdx.x;    // frag id, total 229376
    int l  = f / 57344, fl = f % 57344;
    const float* src; int sk, so, KS, q;
    if (fl < 4096)        { int tap = fl >> 11; q = fl & 2047; KS = 4;
                            src = cq + (size_t)l*49152 + tap;            sk = 3;   so = 384; }
    else if (fl < 12288)  { int j = (fl - 4096) >> 11; q = fl & 2047; KS = 4;
                            src = sa + (size_t)(l*4 + j)*16384;          sk = 128; so = 1;   }
    else if (fl < 24576)  { int ct = (fl - 12288) >> 11; q = fl & 2047; KS = 4;
                            int ci = ct / 3, tap = ct % 3;
                            src = ck + (size_t)(l*2 + ci)*49152 + tap;   sk = 3;   so = 384; }
    else if (fl < 40960)  { int cj = (fl - 24576) >> 11; q = fl & 2047; KS = 4;
                            src = ca + (size_t)(l*8 + cj)*16384;         sk = 128; so = 1;   }
    else if (fl < 49152)  { q = fl - 40960; KS = 4;
                            src = f1 + (size_t)l*65536;                  sk = 512; so = 1;   }
    else                  { q = fl - 49152; KS = 16;
                            src = f2 + (size_t)l*65536;                  sk = 128; so = 1;   }
    int lane = q & 63, tt = q >> 6;
    int ks = tt % KS, ntile = tt / KS;
    int k0 = ks*32 + ((lane >> 4) << 3);
    int o  = ntile*16 + (lane & 15);
    us8 w;
    #pragma unroll
    for (int i = 0; i < 8; i++) w[i] = f2bf(src[(size_t)(k0 + i)*sk + (size_t)o*so]);
    *(us8*)(wp + (size_t)f*8) = w;
}

// ---------------- device helpers ----------------
__device__ __forceinline__ void stage48(const float* __restrict__ src, u16* dst, int t) {
    for (int i = t; i < 1536; i += 256) {
        const float4 v = ((const float4*)src)[i];
        int elem = i << 2;
        int row = elem >> 7, colb = (elem & 127) << 1;
        us4 w; w[0] = f2bf(v.x); w[1] = f2bf(v.y); w[2] = f2bf(v.z); w[3] = f2bf(v.w);
        *(us4*)((char*)dst + (((row << 8) + colb) ^ ((row & 7) << 4))) = w;
    }
}

__device__ __forceinline__ void stage48_embed(const float* __restrict__ x,
    const float* __restrict__ ew, const float* __restrict__ eb,
    const float* __restrict__ pe, int bn0, u16* dst, int t) {
    for (int i = t; i < 1536; i += 256) {
        int elem = i << 2;
        int row = elem >> 7, col = elem & 127;
        int g = row / 12, s = row - g*12;
        int bn = bn0 + g, b = bn / N_, n = bn - b*N_;
        float xv = x[(b*S_ + s)*N_ + n];
        const float4 w  = *(const float4*)(ew + col);
        const float4 bb = *(const float4*)(eb + col);
        const float4 p  = *(const float4*)(pe + s*E_ + col);
        us4 o; o[0] = f2bf(xv*w.x + bb.x + p.x); o[1] = f2bf(xv*w.y + bb.y + p.y);
               o[2] = f2bf(xv*w.z + bb.z + p.z); o[3] = f2bf(xv*w.w + bb.w + p.w);
        *(us4*)((char*)dst + (((row << 8) + (col << 1)) ^ ((row & 7) << 4))) = o;
    }
}

__device__ __forceinline__ void acc_init(f32x4 (&acc)[3][2], const float* bias, int wave, int lane) {
    #pragma unroll
    for (int nl = 0; nl < 2; nl++) {
        float bv = bias ? bias[(wave*2 + nl)*16 + (lane & 15)] : 0.f;
        #pragma unroll
        for (int mt = 0; mt < 3; mt++) {
            acc[mt][nl][0] = bv; acc[mt][nl][1] = bv; acc[mt][nl][2] = bv; acc[mt][nl][3] = bv;
        }
    }
}

// GEMM: D[48][cols of this wave] += A[48][128] * W ; A swizzled bf16 LDS (256B rows)
template<int KSTOT>
__device__ __forceinline__ void gemm48(const u16* A, const us8* __restrict__ WP, int ksOff,
                                       f32x4 (&acc)[3][2], int wave, int lane) {
    #pragma unroll
    for (int ks = 0; ks < 4; ks++) {
        bf16x8 a[3];
        #pragma unroll
        for (int mt = 0; mt < 3; mt++) {
            int row  = mt*16 + (lane & 15);
            int colb = (ks*32 + ((lane >> 4) << 3)) << 1;
            FragU fu; fu.u = *(const us8*)((const char*)A + (((row << 8) + colb) ^ ((row & 7) << 4)));
            a[mt] = fu.b;
        }
        #pragma unroll
        for (int nl = 0; nl < 2; nl++) {
            FragU fb; fb.u = WP[((wave*2 + nl)*KSTOT + ksOff + ks)*64 + lane];
            #pragma unroll
            for (int mt = 0; mt < 3; mt++)
                acc[mt][nl] = __builtin_amdgcn_mfma_f32_16x16x32_bf16(a[mt], fb.b, acc[mt][nl], 0, 0, 0);
        }
    }
}

// GEMM with per-mtile shifted source rows (conv taps; sr<0 -> zero row)
__device__ __forceinline__ void gemm48_rows(const u16* A, const u16* ZR, const int (&sr)[3],
                                            const us8* __restrict__ WP,
                                            f32x4 (&acc)[3][2], int wave, int lane) {
    #pragma unroll
    for (int ks = 0; ks < 4; ks++) {
        bf16x8 a[3];
        #pragma unroll
        for (int mt = 0; mt < 3; mt++) {
            int colb = (ks*32 + ((lane >> 4) << 3)) << 1;
            const char* p = (sr[mt] >= 0)
                ? (const char*)A + (((sr[mt] << 8) + colb) ^ ((sr[mt] & 7) << 4))
                : (const char*)ZR + colb;
            FragU fu; fu.u = *(const us8*)p;
            a[mt] = fu.b;
        }
        #pragma unroll
        for (int nl = 0; nl < 2; nl++) {
            FragU fb; fb.u = WP[((wave*2 + nl)*4 + ks)*64 + lane];
            #pragma unroll
            for (int mt = 0; mt < 3; mt++)
                acc[mt][nl] = __builtin_amdgcn_mfma_f32_16x16x32_bf16(a[mt], fb.b, acc[mt][nl], 0, 0, 0);
        }
    }
}

template<bool RELU>
__device__ __forceinline__ void acc_store_bf(const f32x4 (&acc)[3][2], u16* Bp, int wave, int lane) {
    #pragma unroll
    for (int mt = 0; mt < 3; mt++)
    #pragma unroll
    for (int nl = 0; nl < 2; nl++)
    #pragma unroll
    for (int r = 0; r < 4; r++) {
        int row = mt*16 + ((lane >> 4) << 2) + r;
        int col = (wave*2 + nl)*16 + (lane & 15);
        float v = acc[mt][nl][r];
        if (RELU) v = fmaxf(v, 0.f);
        *(u16*)((char*)Bp + (((row << 8) + (col << 1)) ^ ((row & 7) << 4))) = f2bf(v);
    }
}

__device__ __forceinline__ void ld16(const u16* Bf, int row, int colb, float* o16) {
    int x = (row & 7) << 4;
    int base = (row << 8) + colb;
    us8 u0 = *(const us8*)((const char*)Bf + (base ^ x));
    us8 u1 = *(const us8*)((const char*)Bf + ((base + 16) ^ x));
    #pragma unroll
    for (int d = 0; d < 8; d++) { o16[d] = bf2f(u0[d]); o16[8+d] = bf2f(u1[d]); }
}

// 384 tasks = 4bn x 8heads x 12 qrows; Q tile replaced in place by attention output
template<bool MASK>
__device__ __forceinline__ void attn48(u16* QA, const u16* KB, const u16* VB, int t) {
    #pragma unroll
    for (int it = 0; it < 2; it++) {
        int task = t + it*256;
        if (task < 384) {
            int g = task / 96, rem = task % 96;
            int hh = rem / 12, qi = rem % 12;
            int hb2 = hh << 5;
            int rq = g*12 + qi;
            float qv[16]; ld16(QA, rq, hb2, qv);
            float sc[12]; float mx = -1e30f;
            #pragma unroll
            for (int j = 0; j < 12; j++) {
                float kv[16]; ld16(KB, g*12 + j, hb2, kv);
                float s = 0.f;
                #pragma unroll
                for (int d = 0; d < 16; d++) s += qv[d]*kv[d];
                s *= 0.25f;
                if (MASK && j > qi) s = -1e30f;
                sc[j] = s; mx = fmaxf(mx, s);
            }
            float sum = 0.f;
            #pragma unroll
            for (int j = 0; j < 12; j++) { sc[j] = expf(sc[j] - mx); sum += sc[j]; }
            float inv = 1.f/sum;
            float ov[16];
            #pragma unroll
            for (int d = 0; d < 16; d++) ov[d] = 0.f;
            #pragma unroll
            for (int j = 0; j < 12; j++) {
                float vv[16]; ld16(VB, g*12 + j, hb2, vv);
                #pragma unroll
                for (int d = 0; d < 16; d++) ov[d] += sc[j]*vv[d];
            }
            int x = (rq & 7) << 4;
            us8 w0, w1;
            #pragma unroll
            for (int d = 0; d < 8; d++) { w0[d] = f2bf(ov[d]*inv); w1[d] = f2bf(ov[8+d]*inv); }
            *(us8*)((char*)QA + (((rq << 8) + hb2) ^ x))      = w0;
            *(us8*)((char*)QA + (((rq << 8) + hb2 + 16) ^ x)) = w1;
        }
    }
}

// in-register LN over MFMA D-layout regs; lnbuf = float[48*4*2]; contains one barrier
__device__ __forceinline__ void ln_inreg(f32x4 (&v)[3][2], float* lnbuf,
                                         const float* __restrict__ g, const float* __restrict__ bb,
                                         int wave, int lane) {
    float gc[2], bc[2];
    #pragma unroll
    for (int nl = 0; nl < 2; nl++) {
        int col = (wave*2 + nl)*16 + (lane & 15);
        gc[nl] = g[col]; bc[nl] = bb[col];
    }
    #pragma unroll
    for (int mt = 0; mt < 3; mt++)
    #pragma unroll
    for (int r = 0; r < 4; r++) {
        float a = v[mt][0][r], c = v[mt][1][r];
        float p = a + c, q = a*a + c*c;
        #pragma unroll
        for (int off = 1; off < 16; off <<= 1) { p += __shfl_xor(p, off); q += __shfl_xor(q, off); }
        if ((lane & 15) == 0) {
            int row = mt*16 + ((lane >> 4) << 2) + r;
            lnbuf[(row*4 + wave)*2]     = p;
            lnbuf[(row*4 + wave)*2 + 1] = q;
        }
    }
    __syncthreads();
    #pragma unroll
    for (int mt = 0; mt < 3; mt++)
    #pragma unroll
    for (int r = 0; r < 4; r++) {
        int row = mt*16 + ((lane >> 4) << 2) + r;
        float sum = 0.f, ss = 0.f;
        #pragma unroll
        for (int w2 = 0; w2 < 4; w2++) { sum += lnbuf[(row*4 + w2)*2]; ss += lnbuf[(row*4 + w2)*2 + 1]; }
        float m   = sum * (1.f/128.f);
        float var = ss * (1.f/128.f) - m*m;
        float inv = rsqrtf(var + EPS_);
        #pragma unroll
        for (int nl = 0; nl < 2; nl++)
            v[mt][nl][r] = (v[mt][nl][r] - m)*inv*gc[nl] + bc[nl];
    }
}

// ---------------- whole decoder layer, fused (4 bn per block, 4 waves, nt-split) ----------------
template<bool EMB, bool FIN>
__global__ void __launch_bounds__(256, 3)
k_layer(float* __restrict__ h, const float* __restrict__ x,
        const float* __restrict__ ew, const float* __restrict__ ebp, const float* __restrict__ pe,
        const float* __restrict__ encx, const u16* __restrict__ lw,
        const float* __restrict__ sab, const float* __restrict__ ckb, const float* __restrict__ cab,
        const float* __restrict__ fb1, const float* __restrict__ fb2,
        const float* __restrict__ lg, const float* __restrict__ lb,
        const float* __restrict__ fcw, const float* __restrict__ fcb,
        float* __restrict__ outp) {
    __shared__ __align__(16) u16 P0[6144], P1[6144], P2[6144], P3[6144], ZR[128];
    __shared__ __align__(16) float lnbuf[48*4*2];

    int t = threadIdx.x, wave = t >> 6, lane = t & 63;
    int bid = blockIdx.x;
    float* hp = h + (size_t)bid * (48*128);

    if (t < 64) ((unsigned*)ZR)[t] = 0;
    if (EMB) stage48_embed(x, ew, ebp, pe, bid*4, P0, t);
    else     stage48(hp, P0, t);
    __syncthreads();                                               // 1

    int gg[3], rr[3];
    #pragma unroll
    for (int mt = 0; mt < 3; mt++) { int m = mt*16 + (lane & 15); gg[mt] = m/12; rr[mt] = m - gg[mt]*12; }

    // ---- SELF: causal conv (residual in regs) ----
    f32x4 cacc[3][2];
    acc_init(cacc, nullptr, wave, lane);
    {
        int sr[3];
        #pragma unroll
        for (int mt = 0; mt < 3; mt++) { int r2 = rr[mt] - 1; sr[mt] = (r2 >= 0) ? gg[mt]*12 + r2 : -1; }
        gemm48_rows(P0, ZR, sr, (const us8*)lw, cacc, wave, lane);
        #pragma unroll
        for (int mt = 0; mt < 3; mt++) sr[mt] = gg[mt]*12 + rr[mt];
        gemm48_rows(P0, ZR, sr, (const us8*)(lw + 16384), cacc, wave, lane);
    }
    acc_store_bf<false>(cacc, P1, wave, lane);                     // C
    __syncthreads();                                               // 2

    {   // QKV from conv output
        const us8* sap = (const us8*)(lw + 32768);
        f32x4 a[3][2];
        acc_init(a, sab, wave, lane);        gemm48<4>(P1, sap,        0, a, wave, lane); acc_store_bf<false>(a, P0, wave, lane);
        acc_init(a, sab + 128, wave, lane);  gemm48<4>(P1, sap + 2048, 0, a, wave, lane); acc_store_bf<false>(a, P2, wave, lane);
        acc_init(a, sab + 256, wave, lane);  gemm48<4>(P1, sap + 4096, 0, a, wave, lane); acc_store_bf<false>(a, P3, wave, lane);
    }
    __syncthreads();                                               // 3
    attn48<true>(P0, P2, P3, t);
    __syncthreads();                                               // 4

    f32x4 hres[3][2];
    {   // out-proj + residual
        f32x4 a[3][2];
        acc_init(a, sab + 384, wave, lane);
        gemm48<4>(P0, (const us8*)(lw + 81920), 0, a, wave, lane);
        #pragma unroll
        for (int mt = 0; mt < 3; mt++)
        #pragma unroll
        for (int nl = 0; nl < 2; nl++) hres[mt][nl] = a[mt][nl] + cacc[mt][nl];
    }
    ln_inreg(hres, lnbuf, lg, lb, wave, lane);                     // 5 (internal)
    acc_store_bf<false>(hres, P1, wave, lane);                     // h1 (Q input for cross)
    stage48(encx + (size_t)(bid*4) * (S_*E_), P2, t);              // enc0
    __syncthreads();                                               // 6

    // ---- CROSS (2 encoders, averaged) ----
    f32x4 creg[3][2];
    #pragma unroll
    for (int nl = 0; nl < 2; nl++) {
        int col = (wave*2 + nl)*16 + (lane & 15);
        float bv = cab[3*128 + col] + cab[7*128 + col];
        #pragma unroll
        for (int mt = 0; mt < 3; mt++) { creg[mt][nl][0]=bv; creg[mt][nl][1]=bv; creg[mt][nl][2]=bv; creg[mt][nl][3]=bv; }
    }

    #pragma unroll
    for (int ci = 0; ci < 2; ci++) {
        {   // enc conv -> ES (P3)
            f32x4 a[3][2];
            acc_init(a, ckb + ci*128, wave, lane);
            #pragma unroll
            for (int tap = 0; tap < 3; tap++) {
                int sr[3];
                #pragma unroll
                for (int mt = 0; mt < 3; mt++) {
                    int r2 = rr[mt] + tap - 1;
                    sr[mt] = (r2 >= 0 && r2 < 12) ? gg[mt]*12 + r2 : -1;
                }
                gemm48_rows(P2, ZR, sr, (const us8*)(lw + 98304 + (ci*3 + tap)*16384), a, wave, lane);
            }
            acc_store_bf<false>(a, P3, wave, lane);
        }
        __syncthreads();                                           // 7 / 12
        const us8* cap = (const us8*)(lw + 196608 + ci*4*16384);
        f32x4 vr[3][2];
        {
            f32x4 a[3][2];
            acc_init(a, cab + (ci*4 + 0)*128, wave, lane); gemm48<4>(P1, cap,        0, a, wave, lane); acc_store_bf<false>(a, P0, wave, lane);
            acc_init(a, cab + (ci*4 + 1)*128, wave, lane); gemm48<4>(P3, cap + 2048, 0, a, wave, lane); acc_store_bf<false>(a, P2, wave, lane);
            acc_init(vr, cab + (ci*4 + 2)*128, wave, lane); gemm48<4>(P3, cap + 4096, 0, vr, wave, lane);
        }
        __syncthreads();                                           // 8 / 13
        acc_store_bf<false>(vr, P3, wave, lane);
        __syncthreads();                                           // 9 / 14
        attn48<false>(P0, P2, P3, t);
        __syncthreads();                                           // 10 / 15
        gemm48<4>(P0, cap + 6144, 0, creg, wave, lane);            // out-proj accumulate
        if (ci == 0) {
            stage48(encx + ((size_t)BN_ + bid*4) * (S_*E_), P2, t);  // enc1
            __syncthreads();                                       // 11
        }
    }
    #pragma unroll
    for (int mt = 0; mt < 3; mt++)
    #pragma unroll
    for (int nl = 0; nl < 2; nl++) hres[mt][nl] = hres[mt][nl] + 0.5f*creg[mt][nl];
    __syncthreads();                                               // 16 (guard lnbuf + P1 rewrite)
    ln_inreg(hres, lnbuf, lg + 128, lb + 128, wave, lane);         // 17 (internal)
    acc_store_bf<false>(hres, P1, wave, lane);                     // h2 (FFN input)
    __syncthreads();                                               // 18

    // ---- FFN (chunked mid, ping-pong P2/P3) ----
    f32x4 ffacc[3][2];
    acc_init(ffacc, fb2, wave, lane);
    #pragma unroll
    for (int c = 0; c < 4; c++) {
        u16* MB = (c & 1) ? P3 : P2;
        {
            f32x4 a[3][2];
            acc_init(a, fb1 + c*128, wave, lane);
            gemm48<4>(P1, (const us8*)(lw + 327680) + c*2048, 0, a, wave, lane);
            acc_store_bf<true>(a, MB, wave, lane);
        }
        __syncthreads();                                           // 19..22
        gemm48<16>(MB, (const us8*)(lw + 393216), c*4, ffacc, wave, lane);
    }
    #pragma unroll
    for (int mt = 0; mt < 3; mt++)
    #pragma unroll
    for (int nl = 0; nl < 2; nl++) hres[mt][nl] = hres[mt][nl] + ffacc[mt][nl];
    ln_inreg(hres, lnbuf, lg + 256, lb + 256, wave, lane);         // 23 (internal)

    if (FIN) {
        // fused final projection (OUT=1) with output transpose
        float fw[2];
        #pragma unroll
        for (int nl = 0; nl < 2; nl++) fw[nl] = fcw[(wave*2 + nl)*16 + (lane & 15)];
        float pr[3][4];
        #pragma unroll
        for (int mt = 0; mt < 3; mt++)
        #pragma unroll
        for (int r = 0; r < 4; r++) {
            float p = hres[mt][0][r]*fw[0] + hres[mt][1][r]*fw[1];
            #pragma unroll
            for (int off = 1; off < 16; off <<= 1) p += __shfl_xor(p, off);
            pr[mt][r] = p;
        }
        __syncthreads();                                           // lnbuf readers done
        if ((lane & 15) == 0) {
            #pragma unroll
            for (int mt = 0; mt < 3; mt++)
            #pragma unroll
            for (int r = 0; r < 4; r++) {
                int row = mt*16 + ((lane >> 4) << 2) + r;
                lnbuf[row*4 + wave] = pr[mt][r];
            }
        }
        __syncthreads();
        if (t < 48) {
            float s4 = lnbuf[t*4] + lnbuf[t*4+1] + lnbuf[t*4+2] + lnbuf[t*4+3] + fcb[0];
            int bn = bid*4 + t/12, s = t % 12;
            int b = bn / N_, n = bn - b*N_;
            outp[(b*S_ + s)*N_ + n] = s4;
        }
    } else {
        #pragma unroll
        for (int mt = 0; mt < 3; mt++)
        #pragma unroll
        for (int nl = 0; nl < 2; nl++)
        #pragma unroll
        for (int r = 0; r < 4; r++) {
            int row = mt*16 + ((lane >> 4) << 2) + r;
            int col = (wave*2 + nl)*16 + (lane & 15);
            hp[row*128 + col] = hres[mt][nl][r];
        }
    }
}

extern "C" void kernel_launch(void* const* d_in, const int* in_sizes, int n_in,
                              void* d_out, int out_size, void* d_ws, size_t ws_size,
                              hipStream_t stream) {
    const float* x        = (const float*)d_in[0];
    const float* enc_x    = (const float*)d_in[1];
    const float* emb_w    = (const float*)d_in[3];
    const float* emb_b    = (const float*)d_in[4];
    const float* pe       = (const float*)d_in[5];
    const float* conv_q_w = (const float*)d_in[6];
    const float* conv_k_w = (const float*)d_in[7];
    const float* conv_k_b = (const float*)d_in[8];
    const float* sa_w     = (const float*)d_in[9];
    const float* sa_b     = (const float*)d_in[10];
    const float* ca_w     = (const float*)d_in[11];
    const float* ca_b     = (const float*)d_in[12];
    const float* ff_w1    = (const float*)d_in[13];
    const float* ff_b1    = (const float*)d_in[14];
    const float* ff_w2    = (const float*)d_in[15];
    const float* ff_b2    = (const float*)d_in[16];
    const float* ln_g     = (const float*)d_in[17];
    const float* ln_b     = (const float*)d_in[18];
    const float* fc_w     = (const float*)d_in[19];
    const float* fc_b     = (const float*)d_in[20];

    const size_t HN = (size_t)BN_ * S_ * E_;
    float* h  = (float*)d_ws;
    u16* wpk  = (u16*)((float*)d_ws + HN);

    k_wpack<<<896, 256, 0, stream>>>(conv_q_w, sa_w, conv_k_w, ca_w, ff_w1, ff_w2, wpk);

    for (int l = 0; l < L_; l++) {
        const u16* lw = wpk + (size_t)l*458752;
        const float* sab = sa_b + l*512;
        const float* ckb = conv_k_b + l*256;
        const float* cab = ca_b + l*1024;
        const float* fb1 = ff_b1 + l*512;
        const float* fb2 = ff_b2 + l*128;
        const float* lg  = ln_g + l*384;
        const float* lb  = ln_b + l*384;
        if (l == 0)
            k_layer<true, false><<<BN_/4, 256, 0, stream>>>(h, x, emb_w, emb_b, pe, enc_x, lw,
                sab, ckb, cab, fb1, fb2, lg, lb, fc_w, fc_b, (float*)d_out);
        else if (l == L_-1)
            k_layer<false, true><<<BN_/4, 256, 0, stream>>>(h, x, emb_w, emb_b, pe, enc_x, lw,
                sab, ckb, cab, fb1, fb2, lg, lb, fc_w, fc_b, (float*)d_out);
        else
            k_layer<false, false><<<BN_/4, 256, 0, stream>>>(h, x, emb_w, emb_b, pe, enc_x, lw,
                sab, ckb, cab, fb1, fb2, lg, lb, fc_w, fc_b, (float*)d_out);
    }
}